// Round 1
// 148.860 us; speedup vs baseline: 1.0431x; 1.0431x over previous
//
#include <hip/hip_runtime.h>
#include <stdint.h>

// Problem constants (reference: N=2048, M=100000, D=128, K=5)
#define N_Q 2048
#define M_B 100000
#define D_DIM 128
#define KNN 5
#define SLABS_TOTAL 1563            // ceil(M/64)
#define M_PAD (SLABS_TOTAL * 64)    // 100032
#define CHUNKS 64
#define SPC 25                      // slabs per chunk (12 pairs + 1 single); chunk 63 empty
#define CLS 16                      // col classes per chunk: col mod 16 (MFMA lane class)
#define FTOT (CHUNKS * CLS)         // 1024 rsm entries per row (phantoms = NEGF)
#define ROWBLOCKS 16
#define TROWS 128                   // rt=2 per wave (R7: rt=4 halved occupancy)
#define BIGF 3.0e38f
#define NEGF -3.0e38f

// Accuracy (R9, refines validated R6/R8 scheme): output = top-5 of per-
// (chunk x col-mod-16 class) bf16 acc maxima -- 1024 candidate classes per
// row vs R8's 832 pair maxima; finer granularity, strictly lower collision
// probability. acc still excludes the row-constant -x^2/2 (cannot change
// per-row argmax); k_scan reconstructs d2 = x2 - 2*acc with fp32 x2.

typedef __attribute__((ext_vector_type(8))) short short8;      // MFMA A/B frag (8 bf16)
typedef __attribute__((ext_vector_type(4))) unsigned short ushort4v;
typedef __attribute__((ext_vector_type(8))) unsigned short ushort8v;
typedef __attribute__((ext_vector_type(4))) float f32x4;       // MFMA C/D frag

static __device__ __forceinline__ unsigned short f2bf(float f) {
  unsigned int u = __builtin_bit_cast(unsigned int, f);
  u = (u + 0x7FFFu + ((u >> 16) & 1u)) >> 16;   // RNE
  return (unsigned short)u;
}

static __device__ __forceinline__ void gload_lds16(const void* g, void* l) {
  __builtin_amdgcn_global_load_lds((const __attribute__((address_space(1))) unsigned int*)g,
                                   (__attribute__((address_space(3))) unsigned int*)l, 16, 0, 0);
}
static __device__ __forceinline__ void gload_lds4(const void* g, void* l) {
  __builtin_amdgcn_global_load_lds((const __attribute__((address_space(1))) unsigned int*)g,
                                   (__attribute__((address_space(3))) unsigned int*)l, 4, 0, 0);
}

#define DPPADD(v, ctrl)                                                              \
  do {                                                                               \
    int _t = __builtin_amdgcn_update_dpp(0, __builtin_bit_cast(int, (v)), (ctrl),    \
                                         0xf, 0xf, false);                           \
    (v) = (v) + __builtin_bit_cast(float, _t);                                       \
  } while (0)

// ---------------------------------------------------------------------------
// K0: bank fp32 -> bf16 slab-tiled + ny2 = -0.5*|y|^2 (pads NEGF).
// Lane-contiguous flat reads; LDS-staged tile; coalesced 16B/lane writes.
// Tiled layout: slab s, unit u = kc*64 + j holds Y[s*64+j][kc*8 .. kc*8+8).
// ---------------------------------------------------------------------------
__global__ __launch_bounds__(256) void k_prep(const float* __restrict__ Y,
                                              unsigned short* __restrict__ ybf,
                                              float* __restrict__ ny2) {
  const int s = blockIdx.x;
  const int t = threadIdx.x;
  __shared__ __align__(16) unsigned short tile[8192];   // 16 KB bf16 slab
  __shared__ float redy[64 * 33];                       // padded
#pragma unroll
  for (int i = 0; i < 8; ++i) {
    const int u = i * 256 + t;                  // flat float4 index in 32KB slab
    const int rowl = u >> 5;                    // 0..63
    const int q = u & 31;                       // float4 within row
    const int rowg = s * 64 + rowl;
    const int rowc = (rowg < M_B) ? rowg : (M_B - 1);
    const float4 v = ((const float4*)Y)[(size_t)rowc * 32 + q];
    redy[rowl * 33 + q] = v.x * v.x + v.y * v.y + v.z * v.z + v.w * v.w;
    ushort4v o;
    o[0] = f2bf(v.x); o[1] = f2bf(v.y); o[2] = f2bf(v.z); o[3] = f2bf(v.w);
    *(ushort4v*)(tile + (size_t)(((q >> 1) * 64 + rowl) * 8 + (q & 1) * 4)) = o;
  }
  __syncthreads();
  {
    const int rowl = t >> 2;                    // quad per row
    const int k = t & 3;
    float ss = 0.f;
#pragma unroll
    for (int j = 0; j < 8; ++j) ss += redy[rowl * 33 + k * 8 + j];
    DPPADD(ss, 0xB1);                           // quad xor1
    DPPADD(ss, 0x4E);                           // quad xor2 -> quad sum
    const int rowg = s * 64 + rowl;
    if ((t & 3) == 0) ny2[(size_t)s * 64 + rowl] = (rowg < M_B) ? (-0.5f * ss) : NEGF;
  }
#pragma unroll
  for (int i = 0; i < 4; ++i) {                 // coalesced 16B/lane global writes
    const int u = i * 256 + t;
    *(ushort8v*)(ybf + ((size_t)s * 1024 + u) * 8) = *(const ushort8v*)(tile + u * 8);
  }
}

// ---------------------------------------------------------------------------
// Main (single MFMA pass): block = 128 rows x one chunk (25 slabs staged as
// 12 pairs + 1 single, 32 KB per barrier). acc = dot - 0.5*y2 (row-constant
// -x^2/2 deferred to k_scan). R9: NO cross-lane reduce in the loop -- the
// MFMA C/D layout pins each lane to col class lm = lane&15, so each lane
// keeps a persistent running max per (row, class) in registers for the whole
// chunk; one register-resident fmax chain per slab. The per-pair DPP reduce
// + pmax_r + divergent lm==pl select of R8 (~80 VALU/pair, ~30% of loop
// VALU) are deleted. Grid 1024 = 4.0 blocks/CU; chunk = bid % 64, 64%8==0:
// all 16 row-blocks of a chunk share bid%8 -> one XCD's L2.
// MFMA layouts (verified m89/m91): A[m=lane&15][k=(lane>>4)*8+j],
// B[n=lane&15][k=(lane>>4)*8+j], C/D col=lane&15 row=(lane>>4)*4+reg.
// ---------------------------------------------------------------------------
__global__ __launch_bounds__(256, 4) void k_main(const float* __restrict__ X,
                                                 const unsigned short* __restrict__ ybf,
                                                 const float* __restrict__ ny2,
                                                 float* __restrict__ rsm) {
  __shared__ __align__(16) char smem[33280];
  unsigned short* ys = (unsigned short*)smem;        // 32768: two bf16 slabs
  float* ny2s = (float*)(smem + 32768);              //   512: 128 floats

  const int bid = blockIdx.x;
  const int chunk = bid % CHUNKS;                    // 0..63 (XCD-local)
  const int rowblock = bid / CHUNKS;                 // 0..15
  const int row0 = rowblock * TROWS;

  const int cs0 = chunk * SPC;
  int nslab = SLABS_TOTAL - cs0;                     // chunk 62: 13; chunk 63: <=0
  if (nslab > SPC) nslab = SPC;

  const int t = threadIdx.x;
  const int wave = t >> 6;
  const int lane = t & 63;
  const int lm = lane & 15;
  const int lq = lane >> 4;

  // ---- A fragments resident in registers (bf16): 32 rows per wave ----
  short8 afrag[2][4];
#pragma unroll
  for (int rt = 0; rt < 2; ++rt)
#pragma unroll
    for (int ks = 0; ks < 4; ++ks) {
      const float* xr = X + (size_t)(row0 + wave * 32 + rt * 16 + lm) * D_DIM + ks * 32 + lq * 8;
      const float4 a = *(const float4*)xr;
      const float4 b = *(const float4*)(xr + 4);
      short8 f;
      f[0] = (short)f2bf(a.x); f[1] = (short)f2bf(a.y);
      f[2] = (short)f2bf(a.z); f[3] = (short)f2bf(a.w);
      f[4] = (short)f2bf(b.x); f[5] = (short)f2bf(b.y);
      f[6] = (short)f2bf(b.z); f[7] = (short)f2bf(b.w);
      afrag[rt][ks] = f;
    }

  // persistent per-(row,class) running max: lane holds class lm, rows via (rt,rr)
  float prmax[2][4];
#pragma unroll
  for (int rt = 0; rt < 2; ++rt)
#pragma unroll
    for (int rr = 0; rr < 4; ++rr) prmax[rt][rr] = NEGF;

  for (int s = 0; s < nslab; s += 2) {
    const int sg0 = cs0 + s;
    const int two = (s + 1 < nslab);
#pragma unroll
    for (int sl = 0; sl < 2; ++sl) {
      if (sl && !two) break;
      const unsigned short* src = ybf + (size_t)(sg0 + sl) * 8192;
#pragma unroll
      for (int i = 0; i < 4; ++i) {
        const int ub = i * 256 + wave * 64;
        gload_lds16(src + (size_t)(ub + lane) * 8, ys + (size_t)(sl * 8192 + ub * 8));
      }
    }
    if (wave == 0) {
      gload_lds4(ny2 + (size_t)sg0 * 64 + lane, ny2s);
      if (two) gload_lds4(ny2 + (size_t)(sg0 + 1) * 64 + lane, ny2s + 64);
    }
    __syncthreads();

#pragma unroll
    for (int sl = 0; sl < 2; ++sl) {
      if (sl && !two) break;
      float y2c[4];
#pragma unroll
      for (int ct = 0; ct < 4; ++ct) y2c[ct] = ny2s[sl * 64 + ct * 16 + lm];

      f32x4 acc[2][4];                               // init = -y2/2 only (no nx2)
#pragma unroll
      for (int rt = 0; rt < 2; ++rt)
#pragma unroll
        for (int ct = 0; ct < 4; ++ct)
#pragma unroll
          for (int rr = 0; rr < 4; ++rr) acc[rt][ct][rr] = y2c[ct];

#pragma unroll
      for (int ct = 0; ct < 4; ++ct) {
        short8 bfr[4];
#pragma unroll
        for (int ks = 0; ks < 4; ++ks)
          bfr[ks] = *(const short8*)(ys + (size_t)(sl * 8192 +
                       (((ks * 4 + lq) * 64 + ct * 16 + lm)) * 8));
#pragma unroll
        for (int rt = 0; rt < 2; ++rt)
#pragma unroll
          for (int ks = 0; ks < 4; ++ks)
            acc[rt][ct] = __builtin_amdgcn_mfma_f32_16x16x32_bf16(afrag[rt][ks], bfr[ks],
                                                                  acc[rt][ct], 0, 0, 0);
      }

      // ct-combine (v_max3 x2) into the persistent running class max
#pragma unroll
      for (int rt = 0; rt < 2; ++rt)
#pragma unroll
        for (int rr = 0; rr < 4; ++rr) {
          const float cm = fmaxf(fmaxf(fmaxf(acc[rt][0][rr], acc[rt][1][rr]),
                                       acc[rt][2][rr]), acc[rt][3][rr]);
          prmax[rt][rr] = fmaxf(prmax[rt][rr], cm);
        }
    }
    __syncthreads();   // WAR before restage
  }

  // ---- rsm write, row-major: rsm[row][chunk*CLS + lm], all 64 lanes ----
#pragma unroll
  for (int rt = 0; rt < 2; ++rt)
#pragma unroll
    for (int rr = 0; rr < 4; ++rr) {
      const int lrow = wave * 32 + rt * 16 + lq * 4 + rr;
      rsm[(size_t)(row0 + lrow) * FTOT + chunk * CLS + lm] = prmax[rt][rr];
    }
}

// ---------------------------------------------------------------------------
// K_scan: one wave per row. x2 = |x_row|^2 (fp32, wave reduce); top-5 largest
// acc over the row's 1024 class maxima (coalesced), per-lane sorted-5 + 5-round
// wave-max merge; d2 = x2 - 2*acc; sqrt/mean/normalize -> out[row].
// ---------------------------------------------------------------------------
__global__ __launch_bounds__(256) void k_scan(const float* __restrict__ rsm,
                                              const float* __restrict__ X,
                                              const float* __restrict__ minp,
                                              const float* __restrict__ maxp,
                                              float* __restrict__ out) {
  const int wave = threadIdx.x >> 6;
  const int lane = threadIdx.x & 63;
  const int row = blockIdx.x * 4 + wave;
  const float* rp = rsm + (size_t)row * FTOT;

  // x2: 2 floats per lane, butterfly sum
  float x2;
  {
    const float a = X[(size_t)row * D_DIM + lane];
    const float b = X[(size_t)row * D_DIM + 64 + lane];
    x2 = a * a + b * b;
#pragma unroll
    for (int off = 1; off < 64; off <<= 1) x2 += __shfl_xor(x2, off);
  }

  float t0 = NEGF, t1 = NEGF, t2 = NEGF, t3 = NEGF, t4 = NEGF;  // descending
  for (int i = lane; i < FTOT; i += 64) {
    const float v = rp[i];
    if (v > t4) {
      float m = v;
      float n3 = fminf(t3, m); m = fmaxf(t3, m);
      float n2 = fminf(t2, m); m = fmaxf(t2, m);
      float n1 = fminf(t1, m); m = fmaxf(t1, m);
      float n0 = fminf(t0, m); m = fmaxf(t0, m);
      t0 = m; t1 = n0; t2 = n1; t3 = n2; t4 = n3;
    }
  }

  int k = 0;
  float sum = 0.f;
#pragma unroll
  for (int r = 0; r < KNN; ++r) {
    float head = (k == 0) ? t0 : (k == 1) ? t1 : (k == 2) ? t2 : (k == 3) ? t3
               : (k == 4) ? t4 : NEGF;
    float m = head;
#pragma unroll
    for (int off = 1; off < 64; off <<= 1) m = fmaxf(m, __shfl_xor(m, off));
    const unsigned long long mask = __ballot(head == m);
    const int first = __ffsll(mask) - 1;
    if (lane == first) ++k;                      // consume exactly one holder
    sum += sqrtf(fmaxf(x2 - 2.f * m, 0.f));      // d = sqrt(x2 - 2*acc)
  }
  if (lane == 0) {
    const float mn = minp[0], mx = maxp[0];
    out[row] = (sum * (1.0f / KNN) - mn) / (mx - mn);
  }
}

extern "C" void kernel_launch(void* const* d_in, const int* in_sizes, int n_in,
                              void* d_out, int out_size, void* d_ws, size_t ws_size,
                              hipStream_t stream) {
  const float* X = (const float*)d_in[0];
  const float* Y = (const float*)d_in[1];
  const float* minp = (const float*)d_in[2];
  const float* maxp = (const float*)d_in[3];
  float* out = (float*)d_out;

  char* ws = (char*)d_ws;
  size_t off = 0;
  unsigned short* ybf = (unsigned short*)(ws + off); off += (size_t)M_PAD * D_DIM * 2;  // 25.6 MB
  float* ny2 = (float*)(ws + off);                   off += (size_t)M_PAD * 4;          // 400 KB
  float* rsm = (float*)(ws + off);                   off += (size_t)N_Q * FTOT * 4;     // 8.4 MB
  // total ~34.4 MB

  k_prep<<<dim3(SLABS_TOTAL), dim3(256), 0, stream>>>(Y, ybf, ny2);
  k_main<<<dim3(ROWBLOCKS * CHUNKS), dim3(256), 0, stream>>>(X, ybf, ny2, rsm);
  k_scan<<<dim3(N_Q / 4), dim3(256), 0, stream>>>(rsm, X, minp, maxp, out);
}

// Round 2
// 146.719 us; speedup vs baseline: 1.0583x; 1.0146x over previous
//
#include <hip/hip_runtime.h>
#include <stdint.h>

// Problem constants (reference: N=2048, M=100000, D=128, K=5)
#define N_Q 2048
#define M_B 100000
#define D_DIM 128
#define KNN 5
#define SLABS_TOTAL 1563            // ceil(M/64)
#define M_PAD (SLABS_TOTAL * 64)    // 100032
#define CHUNKS 64
#define SPC 25                      // slabs per chunk; chunk 63 empty
#define CLS 16                      // col classes per chunk: col mod 16 (MFMA lane class)
#define FTOT (CHUNKS * CLS)         // 1024 rsm entries per row (phantoms = NEGF)
#define ROWBLOCKS 16
#define TROWS 128                   // rt=2 per wave (R7: rt=4 halved occupancy)
#define BIGF 3.0e38f
#define NEGF -3.0e38f

// Accuracy (R9/R10, refines validated R6/R8 scheme): output = top-5 of per-
// (chunk x col-mod-16 class) bf16 acc maxima -- 1024 candidate classes per
// row. acc excludes the row-constant -x^2/2 (cannot change per-row argmax);
// k_scan reconstructs d2 = x2 - 2*acc with fp32 x2. R10 is bit-identical to
// R9 (same candidate set, same fmax reduction order per class).

typedef __attribute__((ext_vector_type(8))) short short8;      // MFMA A/B frag (8 bf16)
typedef __attribute__((ext_vector_type(4))) unsigned short ushort4v;
typedef __attribute__((ext_vector_type(8))) unsigned short ushort8v;
typedef __attribute__((ext_vector_type(4))) float f32x4;       // MFMA C/D frag

static __device__ __forceinline__ unsigned short f2bf(float f) {
  unsigned int u = __builtin_bit_cast(unsigned int, f);
  u = (u + 0x7FFFu + ((u >> 16) & 1u)) >> 16;   // RNE
  return (unsigned short)u;
}

static __device__ __forceinline__ void gload_lds16(const void* g, void* l) {
  __builtin_amdgcn_global_load_lds((const __attribute__((address_space(1))) unsigned int*)g,
                                   (__attribute__((address_space(3))) unsigned int*)l, 16, 0, 0);
}
static __device__ __forceinline__ void gload_lds4(const void* g, void* l) {
  __builtin_amdgcn_global_load_lds((const __attribute__((address_space(1))) unsigned int*)g,
                                   (__attribute__((address_space(3))) unsigned int*)l, 4, 0, 0);
}

#define DPPADD(v, ctrl)                                                              \
  do {                                                                               \
    int _t = __builtin_amdgcn_update_dpp(0, __builtin_bit_cast(int, (v)), (ctrl),    \
                                         0xf, 0xf, false);                           \
    (v) = (v) + __builtin_bit_cast(float, _t);                                       \
  } while (0)

// ---------------------------------------------------------------------------
// K0: bank fp32 -> bf16 slab-tiled + ny2 = -0.5*|y|^2 (pads NEGF).
// Lane-contiguous flat reads; LDS-staged tile; coalesced 16B/lane writes.
// Tiled layout: slab s, unit u = kc*64 + j holds Y[s*64+j][kc*8 .. kc*8+8).
// ---------------------------------------------------------------------------
__global__ __launch_bounds__(256) void k_prep(const float* __restrict__ Y,
                                              unsigned short* __restrict__ ybf,
                                              float* __restrict__ ny2) {
  const int s = blockIdx.x;
  const int t = threadIdx.x;
  __shared__ __align__(16) unsigned short tile[8192];   // 16 KB bf16 slab
  __shared__ float redy[64 * 33];                       // padded
#pragma unroll
  for (int i = 0; i < 8; ++i) {
    const int u = i * 256 + t;                  // flat float4 index in 32KB slab
    const int rowl = u >> 5;                    // 0..63
    const int q = u & 31;                       // float4 within row
    const int rowg = s * 64 + rowl;
    const int rowc = (rowg < M_B) ? rowg : (M_B - 1);
    const float4 v = ((const float4*)Y)[(size_t)rowc * 32 + q];
    redy[rowl * 33 + q] = v.x * v.x + v.y * v.y + v.z * v.z + v.w * v.w;
    ushort4v o;
    o[0] = f2bf(v.x); o[1] = f2bf(v.y); o[2] = f2bf(v.z); o[3] = f2bf(v.w);
    *(ushort4v*)(tile + (size_t)(((q >> 1) * 64 + rowl) * 8 + (q & 1) * 4)) = o;
  }
  __syncthreads();
  {
    const int rowl = t >> 2;                    // quad per row
    const int k = t & 3;
    float ss = 0.f;
#pragma unroll
    for (int j = 0; j < 8; ++j) ss += redy[rowl * 33 + k * 8 + j];
    DPPADD(ss, 0xB1);                           // quad xor1
    DPPADD(ss, 0x4E);                           // quad xor2 -> quad sum
    const int rowg = s * 64 + rowl;
    if ((t & 3) == 0) ny2[(size_t)s * 64 + rowl] = (rowg < M_B) ? (-0.5f * ss) : NEGF;
  }
#pragma unroll
  for (int i = 0; i < 4; ++i) {                 // coalesced 16B/lane global writes
    const int u = i * 256 + t;
    *(ushort8v*)(ybf + ((size_t)s * 1024 + u) * 8) = *(const ushort8v*)(tile + u * 8);
  }
}

// ---------------------------------------------------------------------------
// Main (single MFMA pass): block = 128 rows x one chunk. R10: software-
// pipelined staging (T3+T4). Single-slab granularity, double-buffered 2x16KB
// LDS; raw s_barrier + COUNTED s_waitcnt vmcnt(4) -- slab s+1's 4 loads/wave
// stay in flight across the barrier while slab s computes (32 MFMA). No
// vmcnt(0) drain in the steady loop (the R9 __syncthreads drain was the
// ~50% stall: MfmaUtil 42 / VALU 26 / HBM 6%, all pipes idle at barriers).
// ny2 for the whole chunk (25x64 floats) is preloaded once -> per-wave vmcnt
// counting is exactly 4/slab. T5 setprio(1) wraps the MFMA cluster (waves on
// a SIMD are from different blocks at different phases). LDS 39168B -> still
// 4 blocks/CU. chunk = bid % 64, 64%8==0: all 16 row-blocks of a chunk share
// bid%8 -> one XCD's L2 (FETCH ~17MB).
// MFMA layouts (verified m89/m91): A[m=lane&15][k=(lane>>4)*8+j],
// B[n=lane&15][k=(lane>>4)*8+j], C/D col=lane&15 row=(lane>>4)*4+reg.
// ---------------------------------------------------------------------------
__global__ __launch_bounds__(256, 4) void k_main(const float* __restrict__ X,
                                                 const unsigned short* __restrict__ ybf,
                                                 const float* __restrict__ ny2,
                                                 float* __restrict__ rsm) {
  __shared__ __align__(16) char smem[39168];
  unsigned short* ys = (unsigned short*)smem;        // 32768: two 16KB bf16 slab bufs
  float* ny2s = (float*)(smem + 32768);              //  6400: whole chunk's ny2

  const int bid = blockIdx.x;
  const int chunk = bid % CHUNKS;                    // 0..63 (XCD-local)
  const int rowblock = bid / CHUNKS;                 // 0..15
  const int row0 = rowblock * TROWS;

  const int cs0 = chunk * SPC;
  int nslab = SLABS_TOTAL - cs0;                     // chunk 62: 13; chunk 63: <=0
  if (nslab > SPC) nslab = SPC;
  if (nslab < 0) nslab = 0;

  const int t = threadIdx.x;
  const int wave = t >> 6;
  const int lane = t & 63;
  const int lm = lane & 15;
  const int lq = lane >> 4;

  // ---- A fragments resident in registers (bf16): 32 rows per wave ----
  short8 afrag[2][4];
#pragma unroll
  for (int rt = 0; rt < 2; ++rt)
#pragma unroll
    for (int ks = 0; ks < 4; ++ks) {
      const float* xr = X + (size_t)(row0 + wave * 32 + rt * 16 + lm) * D_DIM + ks * 32 + lq * 8;
      const float4 a = *(const float4*)xr;
      const float4 b = *(const float4*)(xr + 4);
      short8 f;
      f[0] = (short)f2bf(a.x); f[1] = (short)f2bf(a.y);
      f[2] = (short)f2bf(a.z); f[3] = (short)f2bf(a.w);
      f[4] = (short)f2bf(b.x); f[5] = (short)f2bf(b.y);
      f[6] = (short)f2bf(b.z); f[7] = (short)f2bf(b.w);
      afrag[rt][ks] = f;
    }

  // ---- one-time ny2 preload for the whole chunk (64 floats per slab) ----
  for (int j = wave; j < nslab; j += 4)
    gload_lds4(ny2 + (size_t)(cs0 + j) * 64 + lane, ny2s + (size_t)j * 64);
  __syncthreads();   // full drain: afrag loads + ny2 DMA; vmcnt==0 entering loop

  // persistent per-(row,class) running max: lane holds class lm, rows via (rt,rr)
  float prmax[2][4];
#pragma unroll
  for (int rt = 0; rt < 2; ++rt)
#pragma unroll
    for (int rr = 0; rr < 4; ++rr) prmax[rt][rr] = NEGF;

  // ---- prologue: stage slab 0 into buf 0 (4 gload_lds16 per thread) ----
  if (nslab > 0) {
    const unsigned short* src = ybf + (size_t)cs0 * 8192;
#pragma unroll
    for (int i = 0; i < 4; ++i) {
      const int ub = i * 256 + wave * 64;
      gload_lds16(src + (size_t)(ub + lane) * 8, ys + (size_t)ub * 8);
    }
  }

  for (int s = 0; s < nslab; ++s) {
    unsigned short* yb = ys + (size_t)(s & 1) * 8192;
    if (s + 1 < nslab) {
      // issue next slab's stage into the other buffer (WAR-safe: the last
      // reader of that buffer finished at the previous iteration's barrier2)
      const unsigned short* src = ybf + (size_t)(cs0 + s + 1) * 8192;
      unsigned short* dst = ys + (size_t)((s + 1) & 1) * 8192;
#pragma unroll
      for (int i = 0; i < 4; ++i) {
        const int ub = i * 256 + wave * 64;
        gload_lds16(src + (size_t)(ub + lane) * 8, dst + (size_t)ub * 8);
      }
      // wait only for slab s's 4 loads (oldest); s+1's 4 stay in flight
      asm volatile("s_waitcnt vmcnt(4)" ::: "memory");
    } else {
      asm volatile("s_waitcnt vmcnt(0)" ::: "memory");
    }
    __builtin_amdgcn_s_barrier();   // all waves' slab-s DMA landed -> visible

    float y2c[4];
#pragma unroll
    for (int ct = 0; ct < 4; ++ct) y2c[ct] = ny2s[s * 64 + ct * 16 + lm];

    f32x4 acc[2][4];                               // init = -y2/2 only (no nx2)
#pragma unroll
    for (int rt = 0; rt < 2; ++rt)
#pragma unroll
      for (int ct = 0; ct < 4; ++ct)
#pragma unroll
        for (int rr = 0; rr < 4; ++rr) acc[rt][ct][rr] = y2c[ct];

    __builtin_amdgcn_s_setprio(1);
#pragma unroll
    for (int ct = 0; ct < 4; ++ct) {
      short8 bfr[4];
#pragma unroll
      for (int ks = 0; ks < 4; ++ks)
        bfr[ks] = *(const short8*)(yb + (size_t)(((ks * 4 + lq) * 64 + ct * 16 + lm)) * 8);
#pragma unroll
      for (int rt = 0; rt < 2; ++rt)
#pragma unroll
        for (int ks = 0; ks < 4; ++ks)
          acc[rt][ct] = __builtin_amdgcn_mfma_f32_16x16x32_bf16(afrag[rt][ks], bfr[ks],
                                                                acc[rt][ct], 0, 0, 0);
    }
    __builtin_amdgcn_s_setprio(0);

    // ct-combine into the persistent running class max
#pragma unroll
    for (int rt = 0; rt < 2; ++rt)
#pragma unroll
      for (int rr = 0; rr < 4; ++rr) {
        const float cm = fmaxf(fmaxf(fmaxf(acc[rt][0][rr], acc[rt][1][rr]),
                                     acc[rt][2][rr]), acc[rt][3][rr]);
        prmax[rt][rr] = fmaxf(prmax[rt][rr], cm);
      }

    __builtin_amdgcn_s_barrier();   // all waves done reading buf[s&1] before
                                    // iter s+1 issues stage(s+2) into it
  }

  // ---- rsm write, row-major: rsm[row][chunk*CLS + lm], all 64 lanes ----
#pragma unroll
  for (int rt = 0; rt < 2; ++rt)
#pragma unroll
    for (int rr = 0; rr < 4; ++rr) {
      const int lrow = wave * 32 + rt * 16 + lq * 4 + rr;
      rsm[(size_t)(row0 + lrow) * FTOT + chunk * CLS + lm] = prmax[rt][rr];
    }
}

// ---------------------------------------------------------------------------
// K_scan: one wave per row. x2 = |x_row|^2 (fp32, wave reduce); top-5 largest
// acc over the row's 1024 class maxima (coalesced), per-lane sorted-5 + 5-round
// wave-max merge; d2 = x2 - 2*acc; sqrt/mean/normalize -> out[row].
// ---------------------------------------------------------------------------
__global__ __launch_bounds__(256) void k_scan(const float* __restrict__ rsm,
                                              const float* __restrict__ X,
                                              const float* __restrict__ minp,
                                              const float* __restrict__ maxp,
                                              float* __restrict__ out) {
  const int wave = threadIdx.x >> 6;
  const int lane = threadIdx.x & 63;
  const int row = blockIdx.x * 4 + wave;
  const float* rp = rsm + (size_t)row * FTOT;

  // x2: 2 floats per lane, butterfly sum
  float x2;
  {
    const float a = X[(size_t)row * D_DIM + lane];
    const float b = X[(size_t)row * D_DIM + 64 + lane];
    x2 = a * a + b * b;
#pragma unroll
    for (int off = 1; off < 64; off <<= 1) x2 += __shfl_xor(x2, off);
  }

  float t0 = NEGF, t1 = NEGF, t2 = NEGF, t3 = NEGF, t4 = NEGF;  // descending
  for (int i = lane; i < FTOT; i += 64) {
    const float v = rp[i];
    if (v > t4) {
      float m = v;
      float n3 = fminf(t3, m); m = fmaxf(t3, m);
      float n2 = fminf(t2, m); m = fmaxf(t2, m);
      float n1 = fminf(t1, m); m = fmaxf(t1, m);
      float n0 = fminf(t0, m); m = fmaxf(t0, m);
      t0 = m; t1 = n0; t2 = n1; t3 = n2; t4 = n3;
    }
  }

  int k = 0;
  float sum = 0.f;
#pragma unroll
  for (int r = 0; r < KNN; ++r) {
    float head = (k == 0) ? t0 : (k == 1) ? t1 : (k == 2) ? t2 : (k == 3) ? t3
               : (k == 4) ? t4 : NEGF;
    float m = head;
#pragma unroll
    for (int off = 1; off < 64; off <<= 1) m = fmaxf(m, __shfl_xor(m, off));
    const unsigned long long mask = __ballot(head == m);
    const int first = __ffsll(mask) - 1;
    if (lane == first) ++k;                      // consume exactly one holder
    sum += sqrtf(fmaxf(x2 - 2.f * m, 0.f));      // d = sqrt(x2 - 2*acc)
  }
  if (lane == 0) {
    const float mn = minp[0], mx = maxp[0];
    out[row] = (sum * (1.0f / KNN) - mn) / (mx - mn);
  }
}

extern "C" void kernel_launch(void* const* d_in, const int* in_sizes, int n_in,
                              void* d_out, int out_size, void* d_ws, size_t ws_size,
                              hipStream_t stream) {
  const float* X = (const float*)d_in[0];
  const float* Y = (const float*)d_in[1];
  const float* minp = (const float*)d_in[2];
  const float* maxp = (const float*)d_in[3];
  float* out = (float*)d_out;

  char* ws = (char*)d_ws;
  size_t off = 0;
  unsigned short* ybf = (unsigned short*)(ws + off); off += (size_t)M_PAD * D_DIM * 2;  // 25.6 MB
  float* ny2 = (float*)(ws + off);                   off += (size_t)M_PAD * 4;          // 400 KB
  float* rsm = (float*)(ws + off);                   off += (size_t)N_Q * FTOT * 4;     // 8.4 MB
  // total ~34.4 MB

  k_prep<<<dim3(SLABS_TOTAL), dim3(256), 0, stream>>>(Y, ybf, ny2);
  k_main<<<dim3(ROWBLOCKS * CHUNKS), dim3(256), 0, stream>>>(X, ybf, ny2, rsm);
  k_scan<<<dim3(N_Q / 4), dim3(256), 0, stream>>>(rsm, X, minp, maxp, out);
}